// Round 6
// baseline (1137.277 us; speedup 1.0000x reference)
//
#include <hip/hip_runtime.h>
#include <hip/hip_bf16.h>

#define DIM 48
#define HSP 64            // padded hs row stride in shorts (128B rows, line-aligned)
#define BKN 128           // nodes per bucket (pow2 -> shift/mask)
#define NB1MAX 800        // max buckets (N <= 102400)
#define NBLK 512          // partition blocks / chunks
#define ACCS 49           // LDS acc row stride (odd -> conflict-free banks)
#define AGG_THREADS 512

// ---- pass 1: per-chunk bucket histogram bh[blk][b] (no zeroing needed) ----
__global__ void k_bh(const int* __restrict__ col, int* __restrict__ bh, int E, int nb1) {
    __shared__ int h[NB1MAX];
    for (int i = threadIdx.x; i < nb1; i += blockDim.x) h[i] = 0;
    __syncthreads();
    int chunk = (E + NBLK - 1) / NBLK;
    int lo = blockIdx.x * chunk, hi = min(lo + chunk, E);
    for (int e = lo + threadIdx.x; e < hi; e += blockDim.x)
        atomicAdd(&h[col[e] >> 7], 1);
    __syncthreads();
    int* r = bh + (size_t)blockIdx.x * nb1;
    for (int i = threadIdx.x; i < nb1; i += blockDim.x) r[i] = h[i];
}

// ---- pass 2: per-bucket column scan over the NBLK chunks ----
__global__ void k_colscan(int* __restrict__ bh, int* __restrict__ coltot, int nb1) {
    __shared__ int sm[NBLK];
    int b = blockIdx.x, t = threadIdx.x;
    sm[t] = bh[(size_t)t * nb1 + b];
    __syncthreads();
    int val = sm[t];
    for (int off = 1; off < NBLK; off <<= 1) {
        int v = (t >= off) ? sm[t - off] : 0;
        __syncthreads();
        sm[t] += v;
        __syncthreads();
    }
    bh[(size_t)t * nb1 + b] = sm[t] - val;   // exclusive within column
    if (t == NBLK - 1) coltot[b] = sm[t];
}

// ---- pass 3: bucket-level scan -> bstart; zero g ----
__global__ void k_scan1(const int* __restrict__ coltot, int* __restrict__ bstart,
                        float* __restrict__ g, int nb1, int E) {
    __shared__ int sm[1024];
    int t = threadIdx.x;
    sm[t] = (t < nb1) ? coltot[t] : 0;
    __syncthreads();
    for (int off = 1; off < 1024; off <<= 1) {
        int v = (t >= off) ? sm[t - off] : 0;
        __syncthreads();
        sm[t] += v;
        __syncthreads();
    }
    if (t < nb1) bstart[t] = (t == 0) ? 0 : sm[t - 1];
    if (t == 0) bstart[nb1] = E;
    if (t < 64) g[t] = 0.0f;
}

// ---- pass 4: single-pass scatter into bucketed 'part' (packed lcol<<24|row) ----
__global__ void k_part2(const int* __restrict__ row, const int* __restrict__ col,
                        const int* __restrict__ bh, const int* __restrict__ bstart,
                        unsigned* __restrict__ part, int E, int nb1) {
    __shared__ int base[NB1MAX];
    __shared__ int lcur[NB1MAX];
    int blk = blockIdx.x, t = threadIdx.x;
    const int* bhr = bh + (size_t)blk * nb1;
    for (int i = t; i < nb1; i += blockDim.x) { base[i] = bstart[i] + bhr[i]; lcur[i] = 0; }
    __syncthreads();
    int chunk = (E + NBLK - 1) / NBLK;
    int lo = blk * chunk, hi = min(lo + chunk, E);
    for (int e = lo + t; e < hi; e += blockDim.x) {
        int c = col[e], r = row[e];
        int b = c >> 7;
        int s = atomicAdd(&lcur[b], 1);
        part[base[b] + s] = ((unsigned)(c & 127) << 24) | (unsigned)r;
    }
}

// ---- per-bucket degree count -> dinv ----
__global__ void k_dcnt(const unsigned* __restrict__ part, const int* __restrict__ bstart,
                       float* __restrict__ dinv, int N, int nb1) {
    __shared__ int cnt[BKN];
    int b = blockIdx.x, t = threadIdx.x;
    if (t < BKN) cnt[t] = 0;
    __syncthreads();
    int elo = bstart[b], ehi = bstart[b + 1];
    for (int e = elo + t; e < ehi; e += blockDim.x)
        atomicAdd(&cnt[part[e] >> 24], 1);
    __syncthreads();
    int node = b * BKN + t;
    if (t < BKN && node < N) dinv[node] = 1.0f / sqrtf((float)(cnt[t] + 1));
}

// round-to-nearest-even f32 -> bf16 pair packed into one uint (lo=a, hi=b)
__device__ inline unsigned int pack_bf2(float a, float b) {
    unsigned int ua = __float_as_uint(a);
    ua = (ua + 0x7fffu + ((ua >> 16) & 1u)) >> 16;
    unsigned int ub = __float_as_uint(b);
    ub = (ub + 0x7fffu + ((ub >> 16) & 1u)) & 0xffff0000u;
    return ua | ub;
}

// hs[i,:] = bf16( (in[i,:] @ W) * dinv[i] ), padded rows of HSP shorts
__global__ void k_mm_scale(const float* __restrict__ in, const float* __restrict__ W,
                           const float* __restrict__ dinv,
                           unsigned short* __restrict__ hs, int n) {
    __shared__ float Ws[DIM * DIM];
    for (int i = threadIdx.x; i < DIM * DIM; i += blockDim.x) Ws[i] = W[i];
    __syncthreads();
    int node = blockIdx.x * blockDim.x + threadIdx.x;
    if (node >= n) return;
    float xr[DIM];
    const float4* xp = (const float4*)(in + (size_t)node * DIM);
    #pragma unroll
    for (int j = 0; j < DIM / 4; ++j) {
        float4 v = xp[j];
        xr[j * 4 + 0] = v.x; xr[j * 4 + 1] = v.y;
        xr[j * 4 + 2] = v.z; xr[j * 4 + 3] = v.w;
    }
    float o[DIM];
    #pragma unroll
    for (int f = 0; f < DIM; ++f) o[f] = 0.0f;
    for (int k = 0; k < DIM; ++k) {
        float xv = xr[k];
        #pragma unroll
        for (int f = 0; f < DIM; ++f) o[f] = fmaf(xv, Ws[k * DIM + f], o[f]);
    }
    float d = dinv[node];
    uint4* hp = (uint4*)(hs + (size_t)node * HSP);
    #pragma unroll
    for (int j = 0; j < DIM / 8; ++j) {
        uint4 v;
        v.x = pack_bf2(o[j * 8 + 0] * d, o[j * 8 + 1] * d);
        v.y = pack_bf2(o[j * 8 + 2] * d, o[j * 8 + 3] * d);
        v.z = pack_bf2(o[j * 8 + 4] * d, o[j * 8 + 5] * d);
        v.w = pack_bf2(o[j * 8 + 6] * d, o[j * 8 + 7] * d);
        hp[j] = v;
    }
}

__device__ inline void bf8_atomic(uint4 v, float* a) {
    atomicAdd(a + 0, __uint_as_float(v.x << 16));
    atomicAdd(a + 1, __uint_as_float(v.x & 0xffff0000u));
    atomicAdd(a + 2, __uint_as_float(v.y << 16));
    atomicAdd(a + 3, __uint_as_float(v.y & 0xffff0000u));
    atomicAdd(a + 4, __uint_as_float(v.z << 16));
    atomicAdd(a + 5, __uint_as_float(v.z & 0xffff0000u));
    atomicAdd(a + 6, __uint_as_float(v.w << 16));
    atomicAdd(a + 7, __uint_as_float(v.w & 0xffff0000u));
}

// Edge-parallel aggregation for one bucket.
// RELU=1: outp[i,:] = leaky(dinv[i]*(acc+self) + bias), f32.
// RELU=0: g[f] += sum_i dinv[i]*(acc+self)[f]   (no per-node output).
template <int RELU>
__global__ __launch_bounds__(AGG_THREADS) void k_agg(
    const unsigned short* __restrict__ hs, const unsigned* __restrict__ part,
    const int* __restrict__ bstart, const float* __restrict__ dinv,
    const float* __restrict__ bias, float* __restrict__ outp,
    float* __restrict__ g, int N, int nb1) {
    __shared__ float acc[BKN * ACCS];
    __shared__ float gsum[DIM];
    int b = blockIdx.x, t = threadIdx.x;
    for (int i = t; i < BKN * ACCS; i += AGG_THREADS) acc[i] = 0.0f;
    if (!RELU && t < DIM) gsum[t] = 0.0f;
    __syncthreads();
    int elo = bstart[b], ehi = bstart[b + 1];
    int gid = t / 6, c = t - gid * 6;        // 6 threads per edge, 16B each
    const int ng = AGG_THREADS / 6;          // 85 groups
    if (gid < ng) {
        int e = elo + gid;
        for (; e + ng < ehi; e += 2 * ng) {  // 2 rows in flight per group
            unsigned p0 = part[e], p1 = part[e + ng];
            uint4 v0 = *(const uint4*)(hs + (size_t)(p0 & 0xffffffu) * HSP + c * 8);
            uint4 v1 = *(const uint4*)(hs + (size_t)(p1 & 0xffffffu) * HSP + c * 8);
            bf8_atomic(v0, &acc[(p0 >> 24) * ACCS + c * 8]);
            bf8_atomic(v1, &acc[(p1 >> 24) * ACCS + c * 8]);
        }
        if (e < ehi) {
            unsigned p0 = part[e];
            uint4 v0 = *(const uint4*)(hs + (size_t)(p0 & 0xffffffu) * HSP + c * 8);
            bf8_atomic(v0, &acc[(p0 >> 24) * ACCS + c * 8]);
        }
    }
    __syncthreads();
    // epilogue: 12 float4-chunks per node
    for (int idx = t; idx < BKN * 12; idx += AGG_THREADS) {
        int node = idx / 12, c4 = idx - node * 12;
        int gnode = b * BKN + node;
        if (gnode >= N) continue;
        float d = dinv[gnode];
        uint2 sv = *(const uint2*)(hs + (size_t)gnode * HSP + c4 * 4);  // self loop
        float s0 = __uint_as_float(sv.x << 16);
        float s1 = __uint_as_float(sv.x & 0xffff0000u);
        float s2 = __uint_as_float(sv.y << 16);
        float s3 = __uint_as_float(sv.y & 0xffff0000u);
        const float* ar = &acc[node * ACCS + c4 * 4];
        float o0 = (ar[0] + s0) * d;
        float o1 = (ar[1] + s1) * d;
        float o2 = (ar[2] + s2) * d;
        float o3 = (ar[3] + s3) * d;
        if (RELU) {
            o0 += bias[c4 * 4 + 0]; o1 += bias[c4 * 4 + 1];
            o2 += bias[c4 * 4 + 2]; o3 += bias[c4 * 4 + 3];
            o0 = (o0 >= 0.f) ? o0 : 0.01f * o0;
            o1 = (o1 >= 0.f) ? o1 : 0.01f * o1;
            o2 = (o2 >= 0.f) ? o2 : 0.01f * o2;
            o3 = (o3 >= 0.f) ? o3 : 0.01f * o3;
            *(float4*)(outp + (size_t)gnode * DIM + c4 * 4) = make_float4(o0, o1, o2, o3);
        } else {
            atomicAdd(&gsum[c4 * 4 + 0], o0);
            atomicAdd(&gsum[c4 * 4 + 1], o1);
            atomicAdd(&gsum[c4 * 4 + 2], o2);
            atomicAdd(&gsum[c4 * 4 + 3], o3);
        }
    }
    if (!RELU) {
        __syncthreads();
        if (t < DIM) atomicAdd(&g[t], gsum[t]);
    }
}

// out[k] = sum_f (g[f] + n*b2[f]) * Wlin[f,k] + blin[k]
__global__ void k_final(const float* __restrict__ g, const float* __restrict__ b2,
                        const float* __restrict__ Wlin, const float* __restrict__ blin,
                        float* __restrict__ out, int n) {
    int k = threadIdx.x;
    if (k < 2) {
        float s = blin[k];
        for (int f = 0; f < DIM; ++f)
            s += (g[f] + (float)n * b2[f]) * Wlin[f * 2 + k];
        out[k] = s;
    }
}

static inline char* alignup(char* p, size_t a) {
    return (char*)(((uintptr_t)p + a - 1) & ~(uintptr_t)(a - 1));
}

extern "C" void kernel_launch(void* const* d_in, const int* in_sizes, int n_in,
                              void* d_out, int out_size, void* d_ws, size_t ws_size,
                              hipStream_t stream) {
    const float* x    = (const float*)d_in[0];
    const int*   ei   = (const int*)d_in[1];
    const float* W1   = (const float*)d_in[2];
    const float* b1   = (const float*)d_in[3];
    const float* W2   = (const float*)d_in[4];
    const float* b2   = (const float*)d_in[5];
    const float* Wlin = (const float*)d_in[6];
    const float* blin = (const float*)d_in[7];
    float* out = (float*)d_out;

    int N = in_sizes[0] / DIM;
    int E = in_sizes[1] / 2;
    const int* row = ei;
    const int* col = ei + E;
    int nb1 = (N + BKN - 1) / BKN;   // 782 for N=100k (<= NB1MAX)

    // workspace layout (16B-aligned slices)
    char* p = (char*)d_ws;
    int* bh = (int*)p;                    p = alignup(p + (size_t)NBLK * nb1 * 4, 16);
    int* coltot = (int*)p;                p = alignup(p + nb1 * 4, 16);
    int* bstart = (int*)p;                p = alignup(p + (nb1 + 1) * 4, 16);
    float* dinv = (float*)p;              p = alignup(p + (size_t)N * 4, 16);
    float* g = (float*)p;                 p = alignup(p + 64 * 4, 16);
    unsigned* part = (unsigned*)p;        p = alignup(p + (size_t)E * 4, 16);
    unsigned short* hs = (unsigned short*)p; p = alignup(p + (size_t)N * HSP * 2, 16);
    float* bufh = (float*)p;              // N*DIM f32

    int nblk = (N + 255) / 256;

    // deterministic two-level partition (shared by both layers)
    k_bh<<<NBLK, 256, 0, stream>>>(col, bh, E, nb1);
    k_colscan<<<nb1, NBLK, 0, stream>>>(bh, coltot, nb1);
    k_scan1<<<1, 1024, 0, stream>>>(coltot, bstart, g, nb1, E);
    k_part2<<<NBLK, 256, 0, stream>>>(row, col, bh, bstart, part, E, nb1);
    k_dcnt<<<nb1, 256, 0, stream>>>(part, bstart, dinv, N, nb1);

    // layer 1
    k_mm_scale<<<nblk, 256, 0, stream>>>(x, W1, dinv, hs, N);
    k_agg<1><<<nb1, AGG_THREADS, 0, stream>>>(hs, part, bstart, dinv, b1, bufh, g, N, nb1);

    // layer 2 (global pool fused into agg; bias folded into k_final)
    k_mm_scale<<<nblk, 256, 0, stream>>>(bufh, W2, dinv, hs, N);
    k_agg<0><<<nb1, AGG_THREADS, 0, stream>>>(hs, part, bstart, dinv, b2, bufh, g, N, nb1);

    // final linear
    k_final<<<1, 64, 0, stream>>>(g, b2, Wlin, blin, out, N);
}

// Round 7
// 197.456 us; speedup vs baseline: 5.7596x; 5.7596x over previous
//
#include <hip/hip_runtime.h>
#include <hip/hip_bf16.h>

#define DIM 48
#define HSP 64            // padded hs row stride in shorts (128B rows, line-aligned)
#define BKN 128           // nodes per bucket (pow2 -> shift/mask)
#define NB1MAX 800        // max buckets (N <= 102400)
#define NBLK 512          // partition blocks / chunks
#define BCAPE 3072        // LDS staging (edges) in k_sort; lambda=2048, +22 sigma
#define GNPB 32           // nodes per gather block
#define GTPN 6            // threads per node (16B bf16x8 chunks)

// ---- pass 1: per-chunk bucket histogram bh[blk][b] ----
__global__ void k_bh(const int* __restrict__ col, int* __restrict__ bh, int E, int nb1) {
    __shared__ int h[NB1MAX];
    for (int i = threadIdx.x; i < nb1; i += blockDim.x) h[i] = 0;
    __syncthreads();
    int chunk = (E + NBLK - 1) / NBLK;
    int lo = blockIdx.x * chunk, hi = min(lo + chunk, E);
    for (int e = lo + threadIdx.x; e < hi; e += blockDim.x)
        atomicAdd(&h[col[e] >> 7], 1);
    __syncthreads();
    int* r = bh + (size_t)blockIdx.x * nb1;
    for (int i = threadIdx.x; i < nb1; i += blockDim.x) r[i] = h[i];
}

// ---- pass 2: per-bucket column scan over the NBLK chunks ----
__global__ void k_colscan(int* __restrict__ bh, int* __restrict__ coltot, int nb1) {
    __shared__ int sm[NBLK];
    int b = blockIdx.x, t = threadIdx.x;
    sm[t] = bh[(size_t)t * nb1 + b];
    __syncthreads();
    int val = sm[t];
    for (int off = 1; off < NBLK; off <<= 1) {
        int v = (t >= off) ? sm[t - off] : 0;
        __syncthreads();
        sm[t] += v;
        __syncthreads();
    }
    bh[(size_t)t * nb1 + b] = sm[t] - val;   // exclusive within column
    if (t == NBLK - 1) coltot[b] = sm[t];
}

// ---- pass 3: bucket-level scan -> bstart; zero g; nodeoff[N]=E ----
__global__ void k_scan1(const int* __restrict__ coltot, int* __restrict__ bstart,
                        float* __restrict__ g, int* __restrict__ nodeoff,
                        int nb1, int N, int E) {
    __shared__ int sm[1024];
    int t = threadIdx.x;
    sm[t] = (t < nb1) ? coltot[t] : 0;
    __syncthreads();
    for (int off = 1; off < 1024; off <<= 1) {
        int v = (t >= off) ? sm[t - off] : 0;
        __syncthreads();
        sm[t] += v;
        __syncthreads();
    }
    if (t < nb1) bstart[t] = (t == 0) ? 0 : sm[t - 1];
    if (t == 0) { bstart[nb1] = E; nodeoff[N] = E; }
    if (t < 64) g[t] = 0.0f;
}

// ---- pass 4: single-pass scatter into bucketed 'part' (packed lcol<<24|row) ----
__global__ void k_part2(const int* __restrict__ row, const int* __restrict__ col,
                        const int* __restrict__ bh, const int* __restrict__ bstart,
                        unsigned* __restrict__ part, int E, int nb1) {
    __shared__ int base[NB1MAX];
    __shared__ int lcur[NB1MAX];
    int blk = blockIdx.x, t = threadIdx.x;
    const int* bhr = bh + (size_t)blk * nb1;
    for (int i = t; i < nb1; i += blockDim.x) { base[i] = bstart[i] + bhr[i]; lcur[i] = 0; }
    __syncthreads();
    int chunk = (E + NBLK - 1) / NBLK;
    int lo = blk * chunk, hi = min(lo + chunk, E);
    for (int e = lo + t; e < hi; e += blockDim.x) {
        int c = col[e], r = row[e];
        int b = c >> 7;
        int s = atomicAdd(&lcur[b], 1);
        part[base[b] + s] = ((unsigned)(c & 127) << 24) | (unsigned)r;
    }
}

// ---- pass 5: per-bucket counting sort -> exact CSR srcs/nodeoff + dinv ----
__global__ void k_sort(const unsigned* __restrict__ part, const int* __restrict__ bstart,
                       int* __restrict__ nodeoff, float* __restrict__ dinv,
                       int* __restrict__ srcs, int N, int nb1) {
    __shared__ int cnt[BKN];
    __shared__ int cur[BKN];
    __shared__ int sc[256];
    __shared__ int outb[BCAPE];
    int b = blockIdx.x, t = threadIdx.x;
    int nlo = b * BKN;
    int elo = bstart[b], ehi = bstart[b + 1];
    int nE = ehi - elo;
    if (t < BKN) cnt[t] = 0;
    __syncthreads();
    for (int e = elo + t; e < ehi; e += blockDim.x)
        atomicAdd(&cnt[part[e] >> 24], 1);
    __syncthreads();
    int v = (t < BKN) ? cnt[t] : 0;
    sc[t] = v;
    __syncthreads();
    for (int off = 1; off < 256; off <<= 1) {
        int u = (t >= off) ? sc[t - off] : 0;
        __syncthreads();
        sc[t] += u;
        __syncthreads();
    }
    int ex = (t == 0) ? 0 : sc[t - 1];
    if (t < BKN && nlo + t < N) {
        nodeoff[nlo + t] = elo + ex;
        dinv[nlo + t] = 1.0f / sqrtf((float)(v + 1));
        cur[t] = ex;
    }
    __syncthreads();
    if (nE <= BCAPE) {
        for (int e = elo + t; e < ehi; e += blockDim.x) {
            unsigned p = part[e];
            int s = atomicAdd(&cur[p >> 24], 1);
            outb[s] = (int)(p & 0xffffffu);
        }
        __syncthreads();
        for (int i = t; i < nE; i += blockDim.x) srcs[elo + i] = outb[i];
    } else {  // overflow fallback (statistically unreachable)
        for (int e = elo + t; e < ehi; e += blockDim.x) {
            unsigned p = part[e];
            int s = atomicAdd(&cur[p >> 24], 1);
            srcs[elo + s] = (int)(p & 0xffffffu);
        }
    }
}

// round-to-nearest-even f32 -> bf16 pair packed into one uint (lo=a, hi=b)
__device__ inline unsigned int pack_bf2(float a, float b) {
    unsigned int ua = __float_as_uint(a);
    ua = (ua + 0x7fffu + ((ua >> 16) & 1u)) >> 16;
    unsigned int ub = __float_as_uint(b);
    ub = (ub + 0x7fffu + ((ub >> 16) & 1u)) & 0xffff0000u;
    return ua | ub;
}

// hs[i,:] = bf16( (in[i,:] @ W) * dinv[i] ), padded rows of HSP shorts
__global__ void k_mm_scale(const float* __restrict__ in, const float* __restrict__ W,
                           const float* __restrict__ dinv,
                           unsigned short* __restrict__ hs, int n) {
    __shared__ float Ws[DIM * DIM];
    for (int i = threadIdx.x; i < DIM * DIM; i += blockDim.x) Ws[i] = W[i];
    __syncthreads();
    int node = blockIdx.x * blockDim.x + threadIdx.x;
    if (node >= n) return;
    float xr[DIM];
    const float4* xp = (const float4*)(in + (size_t)node * DIM);
    #pragma unroll
    for (int j = 0; j < DIM / 4; ++j) {
        float4 v = xp[j];
        xr[j * 4 + 0] = v.x; xr[j * 4 + 1] = v.y;
        xr[j * 4 + 2] = v.z; xr[j * 4 + 3] = v.w;
    }
    float o[DIM];
    #pragma unroll
    for (int f = 0; f < DIM; ++f) o[f] = 0.0f;
    for (int k = 0; k < DIM; ++k) {
        float xv = xr[k];
        #pragma unroll
        for (int f = 0; f < DIM; ++f) o[f] = fmaf(xv, Ws[k * DIM + f], o[f]);
    }
    float d = dinv[node];
    uint4* hp = (uint4*)(hs + (size_t)node * HSP);
    #pragma unroll
    for (int j = 0; j < DIM / 8; ++j) {
        uint4 v;
        v.x = pack_bf2(o[j * 8 + 0] * d, o[j * 8 + 1] * d);
        v.y = pack_bf2(o[j * 8 + 2] * d, o[j * 8 + 3] * d);
        v.z = pack_bf2(o[j * 8 + 4] * d, o[j * 8 + 5] * d);
        v.w = pack_bf2(o[j * 8 + 6] * d, o[j * 8 + 7] * d);
        hp[j] = v;
    }
}

// acc[0..7] += bf16x8 in v
__device__ inline void bf8_acc(uint4 v, float* acc) {
    acc[0] += __uint_as_float(v.x << 16);
    acc[1] += __uint_as_float(v.x & 0xffff0000u);
    acc[2] += __uint_as_float(v.y << 16);
    acc[3] += __uint_as_float(v.y & 0xffff0000u);
    acc[4] += __uint_as_float(v.z << 16);
    acc[5] += __uint_as_float(v.z & 0xffff0000u);
    acc[6] += __uint_as_float(v.w << 16);
    acc[7] += __uint_as_float(v.w & 0xffff0000u);
}

// Node-parallel gather, 6 threads/node, 4-wide unrolled edge loop.
// RELU=1: outp[i,:] = leaky(dinv[i]*sum + bias).  RELU=0: g[f] += dinv[i]*sum (pool fused).
template <int RELU>
__global__ void k_gather(const unsigned short* __restrict__ hs,
                         const int* __restrict__ nodeoff, const int* __restrict__ srcs,
                         const float* __restrict__ dinv, const float* __restrict__ bias,
                         float* __restrict__ outp, float* __restrict__ g, int n) {
    __shared__ float gsum[DIM];
    int t = threadIdx.x;
    if (!RELU && t < DIM) gsum[t] = 0.0f;
    if (!RELU) __syncthreads();
    int local = t / GTPN;
    int c = t - local * GTPN;          // bf16x8 chunk 0..5
    int i = blockIdx.x * GNPB + local;
    bool valid = (i < n);
    float acc[8];
    float d = 0.0f;
    if (valid) {
        int start = nodeoff[i];
        int end = nodeoff[i + 1];
        d = dinv[i];
        const unsigned short* hb = hs + (size_t)c * 8;
        uint4 sv = *(const uint4*)(hb + (size_t)i * HSP);     // self loop
        #pragma unroll
        for (int k = 0; k < 8; ++k) acc[k] = 0.0f;
        bf8_acc(sv, acc);
        int j = start;
        for (; j + 4 <= end; j += 4) {
            int s0 = srcs[j], s1 = srcs[j + 1], s2 = srcs[j + 2], s3 = srcs[j + 3];
            uint4 v0 = *(const uint4*)(hb + (size_t)s0 * HSP);
            uint4 v1 = *(const uint4*)(hb + (size_t)s1 * HSP);
            uint4 v2 = *(const uint4*)(hb + (size_t)s2 * HSP);
            uint4 v3 = *(const uint4*)(hb + (size_t)s3 * HSP);
            bf8_acc(v0, acc); bf8_acc(v1, acc); bf8_acc(v2, acc); bf8_acc(v3, acc);
        }
        for (; j < end; ++j) {
            uint4 v = *(const uint4*)(hb + (size_t)srcs[j] * HSP);
            bf8_acc(v, acc);
        }
    }
    if (RELU) {
        if (valid) {
            float o[8];
            #pragma unroll
            for (int k = 0; k < 8; ++k) {
                float v = acc[k] * d + bias[c * 8 + k];
                o[k] = (v >= 0.0f) ? v : 0.01f * v;
            }
            float4* op = (float4*)(outp + (size_t)i * DIM + c * 8);
            op[0] = make_float4(o[0], o[1], o[2], o[3]);
            op[1] = make_float4(o[4], o[5], o[6], o[7]);
        }
    } else {
        if (valid) {
            #pragma unroll
            for (int k = 0; k < 8; ++k) atomicAdd(&gsum[c * 8 + k], acc[k] * d);
        }
        __syncthreads();
        if (t < DIM) atomicAdd(&g[t], gsum[t]);
    }
}

// out[k] = sum_f (g[f] + n*b2[f]) * Wlin[f,k] + blin[k]
__global__ void k_final(const float* __restrict__ g, const float* __restrict__ b2,
                        const float* __restrict__ Wlin, const float* __restrict__ blin,
                        float* __restrict__ out, int n) {
    int k = threadIdx.x;
    if (k < 2) {
        float s = blin[k];
        for (int f = 0; f < DIM; ++f)
            s += (g[f] + (float)n * b2[f]) * Wlin[f * 2 + k];
        out[k] = s;
    }
}

static inline char* alignup(char* p, size_t a) {
    return (char*)(((uintptr_t)p + a - 1) & ~(uintptr_t)(a - 1));
}

extern "C" void kernel_launch(void* const* d_in, const int* in_sizes, int n_in,
                              void* d_out, int out_size, void* d_ws, size_t ws_size,
                              hipStream_t stream) {
    const float* x    = (const float*)d_in[0];
    const int*   ei   = (const int*)d_in[1];
    const float* W1   = (const float*)d_in[2];
    const float* b1   = (const float*)d_in[3];
    const float* W2   = (const float*)d_in[4];
    const float* b2   = (const float*)d_in[5];
    const float* Wlin = (const float*)d_in[6];
    const float* blin = (const float*)d_in[7];
    float* out = (float*)d_out;

    int N = in_sizes[0] / DIM;
    int E = in_sizes[1] / 2;
    const int* row = ei;
    const int* col = ei + E;
    int nb1 = (N + BKN - 1) / BKN;   // 782 for N=100k (<= NB1MAX)

    // workspace layout (16B-aligned slices)
    char* p = (char*)d_ws;
    int* bh = (int*)p;                    p = alignup(p + (size_t)NBLK * nb1 * 4, 16);
    int* coltot = (int*)p;                p = alignup(p + nb1 * 4, 16);
    int* bstart = (int*)p;                p = alignup(p + (nb1 + 1) * 4, 16);
    int* nodeoff = (int*)p;               p = alignup(p + (size_t)(N + 1) * 4, 16);
    float* dinv = (float*)p;              p = alignup(p + (size_t)N * 4, 16);
    float* g = (float*)p;                 p = alignup(p + 64 * 4, 16);
    unsigned* part = (unsigned*)p;        p = alignup(p + (size_t)E * 4, 16);
    int* srcs = (int*)p;                  p = alignup(p + (size_t)E * 4, 16);
    unsigned short* hs = (unsigned short*)p; p = alignup(p + (size_t)N * HSP * 2, 16);
    float* bufh = (float*)p;              // N*DIM f32

    int nblk = (N + 255) / 256;
    int gblk = (N + GNPB - 1) / GNPB;

    // deterministic two-level partition + per-bucket sort (shared by both layers)
    k_bh<<<NBLK, 256, 0, stream>>>(col, bh, E, nb1);
    k_colscan<<<nb1, NBLK, 0, stream>>>(bh, coltot, nb1);
    k_scan1<<<1, 1024, 0, stream>>>(coltot, bstart, g, nodeoff, nb1, N, E);
    k_part2<<<NBLK, 256, 0, stream>>>(row, col, bh, bstart, part, E, nb1);
    k_sort<<<nb1, 256, 0, stream>>>(part, bstart, nodeoff, dinv, srcs, N, nb1);

    // layer 1
    k_mm_scale<<<nblk, 256, 0, stream>>>(x, W1, dinv, hs, N);
    k_gather<1><<<gblk, GNPB * GTPN, 0, stream>>>(hs, nodeoff, srcs, dinv, b1, bufh, g, N);

    // layer 2 (global pool fused; bias folded into k_final)
    k_mm_scale<<<nblk, 256, 0, stream>>>(bufh, W2, dinv, hs, N);
    k_gather<0><<<gblk, GNPB * GTPN, 0, stream>>>(hs, nodeoff, srcs, dinv, b2, bufh, g, N);

    // final linear
    k_final<<<1, 64, 0, stream>>>(g, b2, Wlin, blin, out, N);
}

// Round 8
// 185.576 us; speedup vs baseline: 6.1283x; 1.0640x over previous
//
#include <hip/hip_runtime.h>
#include <hip/hip_bf16.h>
#include <hip/hip_fp8.h>

#define DIM 48
#define HS8 64            // fp8 row stride in BYTES (48 used, 64B sector aligned)
#define BKN 128           // nodes per bucket (pow2 -> shift/mask)
#define NB1MAX 800        // max buckets (N <= 102400)
#define NBLK 512          // partition blocks / chunks
#define BCAPE 3072        // LDS staging (edges) in k_sort; lambda=2048, +22 sigma
#define GNPB 64           // nodes per gather block
#define GTPN 3            // threads per node (16B fp8x16 chunks)

typedef float v2f __attribute__((ext_vector_type(2)));

// ---- fp8 e4m3 helpers (HW cvt with header fallback) ----
__device__ inline unsigned pack_fp8x4(float a, float b, float c, float d) {
#if __has_builtin(__builtin_amdgcn_cvt_pk_fp8_f32)
    int w = __builtin_amdgcn_cvt_pk_fp8_f32(a, b, 0, false);
    w = __builtin_amdgcn_cvt_pk_fp8_f32(c, d, w, true);
    return (unsigned)w;
#else
    __hip_fp8_e4m3 qa(a), qb(b), qc(c), qd(d);
    return (unsigned)qa.__x | ((unsigned)qb.__x << 8) |
           ((unsigned)qc.__x << 16) | ((unsigned)qd.__x << 24);
#endif
}

__device__ inline void acc_fp8x4(unsigned w, float* acc) {
#if __has_builtin(__builtin_amdgcn_cvt_pk_f32_fp8)
    v2f lo = __builtin_amdgcn_cvt_pk_f32_fp8((int)w, false);
    v2f hi = __builtin_amdgcn_cvt_pk_f32_fp8((int)w, true);
    acc[0] += lo[0]; acc[1] += lo[1]; acc[2] += hi[0]; acc[3] += hi[1];
#else
    __hip_fp8_e4m3 q0, q1, q2, q3;
    q0.__x = (unsigned char)(w & 0xff);
    q1.__x = (unsigned char)((w >> 8) & 0xff);
    q2.__x = (unsigned char)((w >> 16) & 0xff);
    q3.__x = (unsigned char)(w >> 24);
    acc[0] += (float)q0; acc[1] += (float)q1;
    acc[2] += (float)q2; acc[3] += (float)q3;
#endif
}

// ---- pass 1: per-chunk bucket histogram bh[blk][b] ----
__global__ void k_bh(const int* __restrict__ col, int* __restrict__ bh, int E, int nb1) {
    __shared__ int h[NB1MAX];
    for (int i = threadIdx.x; i < nb1; i += blockDim.x) h[i] = 0;
    __syncthreads();
    int chunk = (E + NBLK - 1) / NBLK;
    int lo = blockIdx.x * chunk, hi = min(lo + chunk, E);
    for (int e = lo + threadIdx.x; e < hi; e += blockDim.x)
        atomicAdd(&h[col[e] >> 7], 1);
    __syncthreads();
    int* r = bh + (size_t)blockIdx.x * nb1;
    for (int i = threadIdx.x; i < nb1; i += blockDim.x) r[i] = h[i];
}

// ---- pass 2: per-bucket column scan over the NBLK chunks ----
__global__ void k_colscan(int* __restrict__ bh, int* __restrict__ coltot, int nb1) {
    __shared__ int sm[NBLK];
    int b = blockIdx.x, t = threadIdx.x;
    sm[t] = bh[(size_t)t * nb1 + b];
    __syncthreads();
    int val = sm[t];
    for (int off = 1; off < NBLK; off <<= 1) {
        int v = (t >= off) ? sm[t - off] : 0;
        __syncthreads();
        sm[t] += v;
        __syncthreads();
    }
    bh[(size_t)t * nb1 + b] = sm[t] - val;   // exclusive within column
    if (t == NBLK - 1) coltot[b] = sm[t];
}

// ---- pass 3: bucket-level scan -> bstart; zero g; nodeoff[N]=E ----
__global__ void k_scan1(const int* __restrict__ coltot, int* __restrict__ bstart,
                        float* __restrict__ g, int* __restrict__ nodeoff,
                        int nb1, int N, int E) {
    __shared__ int sm[1024];
    int t = threadIdx.x;
    sm[t] = (t < nb1) ? coltot[t] : 0;
    __syncthreads();
    for (int off = 1; off < 1024; off <<= 1) {
        int v = (t >= off) ? sm[t - off] : 0;
        __syncthreads();
        sm[t] += v;
        __syncthreads();
    }
    if (t < nb1) bstart[t] = (t == 0) ? 0 : sm[t - 1];
    if (t == 0) { bstart[nb1] = E; nodeoff[N] = E; }
    if (t < 64) g[t] = 0.0f;
}

// ---- pass 4: single-pass scatter into bucketed 'part' (packed lcol<<24|row) ----
__global__ void k_part2(const int* __restrict__ row, const int* __restrict__ col,
                        const int* __restrict__ bh, const int* __restrict__ bstart,
                        unsigned* __restrict__ part, int E, int nb1) {
    __shared__ int base[NB1MAX];
    __shared__ int lcur[NB1MAX];
    int blk = blockIdx.x, t = threadIdx.x;
    const int* bhr = bh + (size_t)blk * nb1;
    for (int i = t; i < nb1; i += blockDim.x) { base[i] = bstart[i] + bhr[i]; lcur[i] = 0; }
    __syncthreads();
    int chunk = (E + NBLK - 1) / NBLK;
    int lo = blk * chunk, hi = min(lo + chunk, E);
    for (int e = lo + t; e < hi; e += blockDim.x) {
        int c = col[e], r = row[e];
        int b = c >> 7;
        int s = atomicAdd(&lcur[b], 1);
        part[base[b] + s] = ((unsigned)(c & 127) << 24) | (unsigned)r;
    }
}

// ---- pass 5: per-bucket counting sort -> exact CSR srcs/nodeoff + dinv ----
__global__ void k_sort(const unsigned* __restrict__ part, const int* __restrict__ bstart,
                       int* __restrict__ nodeoff, float* __restrict__ dinv,
                       int* __restrict__ srcs, int N, int nb1) {
    __shared__ int cnt[BKN];
    __shared__ int cur[BKN];
    __shared__ int sc[256];
    __shared__ int outb[BCAPE];
    int b = blockIdx.x, t = threadIdx.x;
    int nlo = b * BKN;
    int elo = bstart[b], ehi = bstart[b + 1];
    int nE = ehi - elo;
    if (t < BKN) cnt[t] = 0;
    __syncthreads();
    for (int e = elo + t; e < ehi; e += blockDim.x)
        atomicAdd(&cnt[part[e] >> 24], 1);
    __syncthreads();
    int v = (t < BKN) ? cnt[t] : 0;
    sc[t] = v;
    __syncthreads();
    for (int off = 1; off < 256; off <<= 1) {
        int u = (t >= off) ? sc[t - off] : 0;
        __syncthreads();
        sc[t] += u;
        __syncthreads();
    }
    int ex = (t == 0) ? 0 : sc[t - 1];
    if (t < BKN && nlo + t < N) {
        nodeoff[nlo + t] = elo + ex;
        dinv[nlo + t] = 1.0f / sqrtf((float)(v + 1));
        cur[t] = ex;
    }
    __syncthreads();
    if (nE <= BCAPE) {
        for (int e = elo + t; e < ehi; e += blockDim.x) {
            unsigned p = part[e];
            int s = atomicAdd(&cur[p >> 24], 1);
            outb[s] = (int)(p & 0xffffffu);
        }
        __syncthreads();
        for (int i = t; i < nE; i += blockDim.x) srcs[elo + i] = outb[i];
    } else {  // overflow fallback (statistically unreachable)
        for (int e = elo + t; e < ehi; e += blockDim.x) {
            unsigned p = part[e];
            int s = atomicAdd(&cur[p >> 24], 1);
            srcs[elo + s] = (int)(p & 0xffffffu);
        }
    }
}

// hs8[i,:] = fp8_e4m3( (in[i,:] @ W) * dinv[i] ), 64B-padded rows
__global__ void k_mm_scale(const float* __restrict__ in, const float* __restrict__ W,
                           const float* __restrict__ dinv,
                           unsigned char* __restrict__ hs8, int n) {
    __shared__ float Ws[DIM * DIM];
    for (int i = threadIdx.x; i < DIM * DIM; i += blockDim.x) Ws[i] = W[i];
    __syncthreads();
    int node = blockIdx.x * blockDim.x + threadIdx.x;
    if (node >= n) return;
    float xr[DIM];
    const float4* xp = (const float4*)(in + (size_t)node * DIM);
    #pragma unroll
    for (int j = 0; j < DIM / 4; ++j) {
        float4 v = xp[j];
        xr[j * 4 + 0] = v.x; xr[j * 4 + 1] = v.y;
        xr[j * 4 + 2] = v.z; xr[j * 4 + 3] = v.w;
    }
    float o[DIM];
    #pragma unroll
    for (int f = 0; f < DIM; ++f) o[f] = 0.0f;
    for (int k = 0; k < DIM; ++k) {
        float xv = xr[k];
        #pragma unroll
        for (int f = 0; f < DIM; ++f) o[f] = fmaf(xv, Ws[k * DIM + f], o[f]);
    }
    float d = dinv[node];
    uint4* hp = (uint4*)(hs8 + (size_t)node * HS8);
    #pragma unroll
    for (int q = 0; q < 3; ++q) {
        uint4 v;
        v.x = pack_fp8x4(o[q*16+ 0]*d, o[q*16+ 1]*d, o[q*16+ 2]*d, o[q*16+ 3]*d);
        v.y = pack_fp8x4(o[q*16+ 4]*d, o[q*16+ 5]*d, o[q*16+ 6]*d, o[q*16+ 7]*d);
        v.z = pack_fp8x4(o[q*16+ 8]*d, o[q*16+ 9]*d, o[q*16+10]*d, o[q*16+11]*d);
        v.w = pack_fp8x4(o[q*16+12]*d, o[q*16+13]*d, o[q*16+14]*d, o[q*16+15]*d);
        hp[q] = v;
    }
}

__device__ inline void acc_fp8x16(uint4 v, float* acc) {
    acc_fp8x4(v.x, acc + 0);
    acc_fp8x4(v.y, acc + 4);
    acc_fp8x4(v.z, acc + 8);
    acc_fp8x4(v.w, acc + 12);
}

// Node-parallel gather, 3 threads/node (16 features each), simple edge loop.
// RELU=1: outp[i,:] = leaky(dinv[i]*sum + bias).  RELU=0: g[f] += dinv[i]*sum (pool fused).
template <int RELU>
__global__ void k_gather(const unsigned char* __restrict__ hs8,
                         const int* __restrict__ nodeoff, const int* __restrict__ srcs,
                         const float* __restrict__ dinv, const float* __restrict__ bias,
                         float* __restrict__ outp, float* __restrict__ g, int n) {
    __shared__ float gsum[DIM];
    int t = threadIdx.x;
    if (!RELU && t < DIM) gsum[t] = 0.0f;
    if (!RELU) __syncthreads();
    int local = t / GTPN;
    int c = t - local * GTPN;          // fp8x16 chunk 0..2
    int i = blockIdx.x * GNPB + local;
    bool valid = (i < n);
    float acc[16];
    float d = 0.0f;
    if (valid) {
        int start = nodeoff[i];
        int end = nodeoff[i + 1];
        d = dinv[i];
        const unsigned char* hb = hs8 + (size_t)c * 16;
        #pragma unroll
        for (int k = 0; k < 16; ++k) acc[k] = 0.0f;
        uint4 sv = *(const uint4*)(hb + (size_t)i * HS8);     // self loop
        acc_fp8x16(sv, acc);
        for (int j = start; j < end; ++j) {
            uint4 v = *(const uint4*)(hb + (size_t)srcs[j] * HS8);
            acc_fp8x16(v, acc);
        }
    }
    if (RELU) {
        if (valid) {
            float o[16];
            #pragma unroll
            for (int k = 0; k < 16; ++k) {
                float v = acc[k] * d + bias[c * 16 + k];
                o[k] = (v >= 0.0f) ? v : 0.01f * v;
            }
            float4* op = (float4*)(outp + (size_t)i * DIM + c * 16);
            op[0] = make_float4(o[0], o[1], o[2], o[3]);
            op[1] = make_float4(o[4], o[5], o[6], o[7]);
            op[2] = make_float4(o[8], o[9], o[10], o[11]);
            op[3] = make_float4(o[12], o[13], o[14], o[15]);
        }
    } else {
        if (valid) {
            #pragma unroll
            for (int k = 0; k < 16; ++k) atomicAdd(&gsum[c * 16 + k], acc[k] * d);
        }
        __syncthreads();
        if (t < DIM) atomicAdd(&g[t], gsum[t]);
    }
}

// out[k] = sum_f (g[f] + n*b2[f]) * Wlin[f,k] + blin[k]
__global__ void k_final(const float* __restrict__ g, const float* __restrict__ b2,
                        const float* __restrict__ Wlin, const float* __restrict__ blin,
                        float* __restrict__ out, int n) {
    int k = threadIdx.x;
    if (k < 2) {
        float s = blin[k];
        for (int f = 0; f < DIM; ++f)
            s += (g[f] + (float)n * b2[f]) * Wlin[f * 2 + k];
        out[k] = s;
    }
}

static inline char* alignup(char* p, size_t a) {
    return (char*)(((uintptr_t)p + a - 1) & ~(uintptr_t)(a - 1));
}

extern "C" void kernel_launch(void* const* d_in, const int* in_sizes, int n_in,
                              void* d_out, int out_size, void* d_ws, size_t ws_size,
                              hipStream_t stream) {
    const float* x    = (const float*)d_in[0];
    const int*   ei   = (const int*)d_in[1];
    const float* W1   = (const float*)d_in[2];
    const float* b1   = (const float*)d_in[3];
    const float* W2   = (const float*)d_in[4];
    const float* b2   = (const float*)d_in[5];
    const float* Wlin = (const float*)d_in[6];
    const float* blin = (const float*)d_in[7];
    float* out = (float*)d_out;

    int N = in_sizes[0] / DIM;
    int E = in_sizes[1] / 2;
    const int* row = ei;
    const int* col = ei + E;
    int nb1 = (N + BKN - 1) / BKN;   // 782 for N=100k (<= NB1MAX)

    // workspace layout (64B-aligned slices)
    char* p = (char*)d_ws;
    int* bh = (int*)p;                    p = alignup(p + (size_t)NBLK * nb1 * 4, 64);
    int* coltot = (int*)p;                p = alignup(p + nb1 * 4, 64);
    int* bstart = (int*)p;                p = alignup(p + (nb1 + 1) * 4, 64);
    int* nodeoff = (int*)p;               p = alignup(p + (size_t)(N + 1) * 4, 64);
    float* dinv = (float*)p;              p = alignup(p + (size_t)N * 4, 64);
    float* g = (float*)p;                 p = alignup(p + 64 * 4, 64);
    unsigned* part = (unsigned*)p;        p = alignup(p + (size_t)E * 4, 64);
    int* srcs = (int*)p;                  p = alignup(p + (size_t)E * 4, 64);
    unsigned char* hs8 = (unsigned char*)p; p = alignup(p + (size_t)N * HS8, 64);
    float* bufh = (float*)p;              // N*DIM f32

    int nblk = (N + 255) / 256;
    int gblk = (N + GNPB - 1) / GNPB;

    // deterministic two-level partition + per-bucket sort (shared by both layers)
    k_bh<<<NBLK, 256, 0, stream>>>(col, bh, E, nb1);
    k_colscan<<<nb1, NBLK, 0, stream>>>(bh, coltot, nb1);
    k_scan1<<<1, 1024, 0, stream>>>(coltot, bstart, g, nodeoff, nb1, N, E);
    k_part2<<<NBLK, 256, 0, stream>>>(row, col, bh, bstart, part, E, nb1);
    k_sort<<<nb1, 256, 0, stream>>>(part, bstart, nodeoff, dinv, srcs, N, nb1);

    // layer 1
    k_mm_scale<<<nblk, 256, 0, stream>>>(x, W1, dinv, hs8, N);
    k_gather<1><<<gblk, GNPB * GTPN, 0, stream>>>(hs8, nodeoff, srcs, dinv, b1, bufh, g, N);

    // layer 2 (global pool fused; bias folded into k_final)
    k_mm_scale<<<nblk, 256, 0, stream>>>(bufh, W2, dinv, hs8, N);
    k_gather<0><<<gblk, GNPB * GTPN, 0, stream>>>(hs8, nodeoff, srcs, dinv, b2, bufh, g, N);

    // final linear
    k_final<<<1, 64, 0, stream>>>(g, b2, Wlin, blin, out, N);
}